// Round 13
// baseline (795.451 us; speedup 1.0000x reference)
//
#include <hip/hip_runtime.h>

#define TT  128
#define CC  256
#define VV  25
#define KK  3
#define GG  9
#define LL  9
#define NCC 60
#define CINN 3
#define TV    (TT*VV)          // 3200 (input x layout)
#define KDIM2 (CC*GG)          // 2304
#define UR    ((TT+8)*32)      // 4352 Ut2 rows: row = (t+8)*32+v
#define YSTR  104              // LDS Yt row stride (shorts)
#define HSTR  264              // LDS sH row stride (shorts), bank-skewed

typedef __attribute__((ext_vector_type(8))) short bf16x8;
typedef __attribute__((ext_vector_type(4))) float f32x4;
typedef unsigned short us16;

#define MFMA __builtin_amdgcn_mfma_f32_16x16x32_bf16

__device__ __forceinline__ us16 f2bf(float f) {
    union { float f; unsigned u; } a; a.f = f;
    unsigned r = a.u + 0x7fff + ((a.u >> 16) & 1);
    return (us16)(r >> 16);
}
__device__ __forceinline__ float bf2f(us16 u) {
    union { unsigned u; float f; } a; a.u = ((unsigned)u) << 16; return a.f;
}
__device__ __forceinline__ bf16x8 ld8(const us16* p) { return *(const bf16x8*)p; }

// ---------------- merged prep kernel ----------------

#define PN1 (LL*KK*CC*CC)
#define PN2 (LL*CC*CC*GG)
#define PN3 (LL*KK*32*32)
#define PN4 (LL*CC*32)
#define PTOT (PN1+PN2+PN3+PN4)

__global__ void k_prep(const float* __restrict__ Wg, const float* __restrict__ Wt,
                       const float* __restrict__ A, const float* __restrict__ imp,
                       const float* __restrict__ bg,
                       us16* __restrict__ Wgb, us16* __restrict__ Wt2b,
                       us16* __restrict__ AlTb, float* __restrict__ bgAl) {
    int i = blockIdx.x * 256 + threadIdx.x;
    if (i < PN1) {
        Wgb[i] = f2bf(Wg[i]);
    } else if (i < PN1 + PN2) {
        int j = i - PN1;
        int kk = j % (CC*GG);
        int o  = (j / (CC*GG)) % CC;
        int l  = j / (CC*CC*GG);
        int g = kk >> 8, c = kk & 255;
        Wt2b[j] = f2bf(Wt[((size_t)(l*CC + o)*CC + c)*GG + g]);
    } else if (i < PN1 + PN2 + PN3) {
        int j = i - PN1 - PN2;
        int v = j & 31, w = (j >> 5) & 31;
        int lk = j >> 10, k = lk % KK, l = lk / KK;
        float val = 0.f;
        if (v < VV && w < VV)
            val = A[(k*VV+v)*VV + w] * imp[((size_t)(l*KK+k)*VV+v)*VV + w];
        AlTb[j] = f2bf(val);
    } else if (i < PTOT) {
        int j = i - PN1 - PN2 - PN3;
        int w = j & 31, c = (j >> 5) & 255, l = j >> 13;
        float s = 0.f;
        if (w < VV) {
            for (int k = 0; k < KK; k++) {
                float col = 0.f;
                for (int v = 0; v < VV; v++)
                    col += A[(k*VV+v)*VV + w] * imp[((size_t)(l*KK+k)*VV+v)*VV + w];
                s += bg[l*KK*CC + k*CC + c] * col;
            }
        }
        bgAl[j] = s;
    }
}

// ---------------- block reduce (sum, sumsq) ----------------

__device__ __forceinline__ void blk_reduce2(float& s, float& q, float* red) {
    #pragma unroll
    for (int off = 32; off; off >>= 1) {
        s += __shfl_down(s, off);
        q += __shfl_down(q, off);
    }
    int lane = threadIdx.x & 63, w = threadIdx.x >> 6;
    if (lane == 0) { red[w] = s; red[4+w] = q; }
    __syncthreads();
    s = red[0]+red[1]+red[2]+red[3];
    q = red[4]+red[5]+red[6]+red[7];
}

// ---- per-frame tcn stage macros (3-deep named rotation, r12-proven style) ----
// wave covers 64 output rows (c = wave*64 .. +63) as 4 m-tiles of 16.
// 6 fragments per stage: 4 A (weights) + 2 B (Ut2 window).

#define TLD(S, it) { \
    int k0_ = (it)*32; \
    S##a0 = ld8(wp0 + k0_); \
    S##a1 = ld8(wp0 + (size_t)16*KDIM2 + k0_); \
    S##a2 = ld8(wp0 + (size_t)32*KDIM2 + k0_); \
    S##a3 = ld8(wp0 + (size_t)48*KDIM2 + k0_); \
    int g_ = k0_ >> 8; \
    const us16* bp_ = Ut2prev + (size_t)((t + 8 - g_)*32 + l16)*CC + (k0_ & 255) + quad*8; \
    S##b0 = ld8(bp_); \
    S##b1 = ld8(bp_ + 16*CC); }
#define TMF(S) { \
    acc[0][0] = MFMA(S##a0, S##b0, acc[0][0],0,0,0); \
    acc[0][1] = MFMA(S##a0, S##b1, acc[0][1],0,0,0); \
    acc[1][0] = MFMA(S##a1, S##b0, acc[1][0],0,0,0); \
    acc[1][1] = MFMA(S##a1, S##b1, acc[1][1],0,0,0); \
    acc[2][0] = MFMA(S##a2, S##b0, acc[2][0],0,0,0); \
    acc[2][1] = MFMA(S##a2, S##b1, acc[2][1],0,0,0); \
    acc[3][0] = MFMA(S##a3, S##b0, acc[3][0],0,0,0); \
    acc[3][1] = MFMA(S##a3, S##b1, acc[3][1],0,0,0); }

// ---------------- fused layer kernel ----------------
// One block per frame (blocks 128..135 write the 8 history pad rows of Ut2next).
// FIRST=1: prologue computes h^0 = fcn_in(LN_in(x_t)).
// FIRST=0: prologue computes the PREVIOUS layer's tcn per-frame (MFMA, K=2304,
//          3-stage named rotation) then h = relu(LN2(tcn+bt) + resid(t-4)).
// Prologue -> sH (LDS, B-operand layout) + HTb (bf16 residual buffer).
// Then: Y = Wg@h (MFMA rotation) -> adjacency (MFMA) -> LN1 -> Ut2next.

template<int FIRST>
__global__ __launch_bounds__(256, 1) void k_layer(
    const float* __restrict__ x, const float* __restrict__ lniw,
    const float* __restrict__ lnib, const float* __restrict__ Win,
    const float* __restrict__ bin,
    const us16* __restrict__ Wt2, const us16* __restrict__ Ut2prev,
    const float* __restrict__ btv,
    const float* __restrict__ ln2w, const float* __restrict__ ln2b,
    const us16* __restrict__ HresidTb,
    const us16* __restrict__ Wgb,
    const us16* __restrict__ AlTb, const float* __restrict__ bgAl,
    const float* __restrict__ lnw, const float* __restrict__ lnb,
    us16* __restrict__ HTb, us16* __restrict__ Ut2next) {

    const int t = blockIdx.x, tid = threadIdx.x;
    if (t >= TT) {                     // 8 history pad frames: relu(ln1_b)
        int tp = t - TT, c = tid;
        #pragma unroll
        for (int w = 0; w < 32; w++) {
            float u = (w < VV) ? fmaxf(lnb[c*VV + w], 0.f) : 0.f;
            Ut2next[(size_t)(tp*32 + w)*CC + c] = f2bf(u);
        }
        return;
    }
    __shared__ __align__(16) us16 Yt[CC*YSTR];     // 53.2 KB
    __shared__ __align__(16) us16 sH[32*HSTR];     // 16.9 KB
    __shared__ float red[8];
    __shared__ float sx[80];
    __shared__ float sh[80];
    const int wave = tid >> 6, lane = tid & 63, quad = lane >> 4, l16 = lane & 15;

    if (FIRST) {
        // ---- h^0 = W_in @ LN_in(x_t) + b_in ----
        if (tid < CINN*VV)
            sx[tid] = x[(size_t)(tid/VV)*TV + t*VV + (tid%VV)];
        __syncthreads();
        float s = 0.f, q = 0.f;
        for (int i = 0; i < CINN*VV; i++) { float v = sx[i]; s += v; q += v*v; }
        float m  = s * (1.f/75.f);
        float var = q * (1.f/75.f) - m*m;
        float rs = rsqrtf(var + 1e-5f);
        if (tid < CINN*VV)
            sh[tid] = (sx[tid]-m)*rs*lniw[tid] + lnib[tid];
        __syncthreads();
        int c = tid;
        float w0 = Win[c*3+0], w1 = Win[c*3+1], w2 = Win[c*3+2], bb = bin[c];
        #pragma unroll
        for (int v = 0; v < VV; v++) {
            float acc = bb + w0*sh[v] + w1*sh[VV+v] + w2*sh[2*VV+v];
            us16 b = f2bf(acc);
            HTb[(size_t)(t*32 + v)*CC + c] = b;
            sH[v*HSTR + c] = b;
        }
        #pragma unroll
        for (int v = VV; v < 32; v++)
            sH[v*HSTR + c] = 0;
        __syncthreads();
    } else {
        // ---- previous layer's tcn (per-frame GEMM, K=2304) ----
        f32x4 acc[4][2];
        #pragma unroll
        for (int mt = 0; mt < 4; mt++) { acc[mt][0] = (f32x4){}; acc[mt][1] = (f32x4){}; }
        const us16* wp0 = Wt2 + (size_t)(wave*64 + l16)*KDIM2 + quad*8;
        bf16x8 tXa0,tXa1,tXa2,tXa3,tXb0,tXb1;
        bf16x8 tYa0,tYa1,tYa2,tYa3,tYb0,tYb1;
        bf16x8 tZa0,tZa1,tZa2,tZa3,tZb0,tZb1;
        TLD(tX, 0); TLD(tY, 1); TLD(tZ, 2);
        #pragma unroll 1
        for (int it = 3; it < 72; it += 3) {
            TMF(tX); TLD(tX, it);
            TMF(tY); TLD(tY, it + 1);
            TMF(tZ); TLD(tZ, it + 2);
        }
        TMF(tX); TMF(tY); TMF(tZ);

        // ---- bias + LN2 stats ----
        float s_ = 0.f, q_ = 0.f;
        #pragma unroll
        for (int mt = 0; mt < 4; mt++)
            #pragma unroll
            for (int nt = 0; nt < 2; nt++)
                #pragma unroll
                for (int r = 0; r < 4; r++) {
                    int c = wave*64 + mt*16 + quad*4 + r;
                    int v = nt*16 + l16;
                    float val = acc[mt][nt][r] + btv[c];
                    acc[mt][nt][r] = val;
                    if (v < VV) { s_ += val; q_ += val*val; }
                }
        blk_reduce2(s_, q_, red);
        float m = s_ * (1.f/6400.f);
        float var = q_ * (1.f/6400.f) - m*m;
        float rs = rsqrtf(var + 1e-5f);
        #pragma unroll
        for (int mt = 0; mt < 4; mt++)
            #pragma unroll
            for (int nt = 0; nt < 2; nt++) {
                int v = nt*16 + l16;
                if (v < VV) {
                    int c0 = wave*64 + mt*16 + quad*4;
                    ushort4 pk;
                    float o[4];
                    #pragma unroll
                    for (int r = 0; r < 4; r++) {
                        int c = c0 + r;
                        float res = (t >= 4) ? bf2f(HresidTb[(size_t)((t-4)*32 + v)*CC + c]) : 0.f;
                        o[r] = fmaxf((acc[mt][nt][r]-m)*rs*ln2w[c*VV+v] + ln2b[c*VV+v] + res, 0.f);
                    }
                    pk.x = f2bf(o[0]); pk.y = f2bf(o[1]); pk.z = f2bf(o[2]); pk.w = f2bf(o[3]);
                    *(ushort4*)(HTb + (size_t)(t*32 + v)*CC + c0) = pk;
                    *(ushort4*)(sH + v*HSTR + c0) = pk;
                }
            }
        #pragma unroll
        for (int v = VV; v < 32; v++)
            sH[v*HSTR + tid] = 0;
        __syncthreads();
    }

    // ---- phase 2 operand prefetch (lands during phase 1) ----
    bf16x8 al[2][3];
    #pragma unroll
    for (int nt = 0; nt < 2; nt++)
        #pragma unroll
        for (int s = 0; s < 3; s++)
            al[nt][s] = ld8(AlTb + (size_t)(s*32 + nt*16 + l16)*32 + quad*8);

    // ---- phase 1: Y = Wg @ h  (M=768, N=32, K=256) ----
    bf16x8 bf[2][8];
    #pragma unroll
    for (int nt = 0; nt < 2; nt++)
        #pragma unroll
        for (int s = 0; s < 8; s++)
            bf[nt][s] = *(const bf16x8*)(sH + (nt*16 + l16)*HSTR + s*32 + quad*8);

    bf16x8 wA0,wA1,wA2,wA3,wA4,wA5,wA6,wA7;
    bf16x8 wB0,wB1,wB2,wB3,wB4,wB5,wB6,wB7;
    bf16x8 wC0,wC1,wC2,wC3,wC4,wC5,wC6,wC7;

#define PLD(S, mtv) { \
    const us16* ap_ = Wgb + (size_t)(wave*192 + (mtv)*16 + l16)*CC + quad*8; \
    S##0 = ld8(ap_);       S##1 = ld8(ap_ + 32); \
    S##2 = ld8(ap_ + 64);  S##3 = ld8(ap_ + 96); \
    S##4 = ld8(ap_ + 128); S##5 = ld8(ap_ + 160); \
    S##6 = ld8(ap_ + 192); S##7 = ld8(ap_ + 224); }
#define PMFW(S, mtv) { \
    f32x4 p0a = {}, p0b = {}, p1a = {}, p1b = {}; \
    p0a = MFMA(S##0, bf[0][0], p0a,0,0,0); \
    p1a = MFMA(S##0, bf[1][0], p1a,0,0,0); \
    p0b = MFMA(S##1, bf[0][1], p0b,0,0,0); \
    p1b = MFMA(S##1, bf[1][1], p1b,0,0,0); \
    p0a = MFMA(S##2, bf[0][2], p0a,0,0,0); \
    p1a = MFMA(S##2, bf[1][2], p1a,0,0,0); \
    p0b = MFMA(S##3, bf[0][3], p0b,0,0,0); \
    p1b = MFMA(S##3, bf[1][3], p1b,0,0,0); \
    p0a = MFMA(S##4, bf[0][4], p0a,0,0,0); \
    p1a = MFMA(S##4, bf[1][4], p1a,0,0,0); \
    p0b = MFMA(S##5, bf[0][5], p0b,0,0,0); \
    p1b = MFMA(S##5, bf[1][5], p1b,0,0,0); \
    p0a = MFMA(S##6, bf[0][6], p0a,0,0,0); \
    p1a = MFMA(S##6, bf[1][6], p1a,0,0,0); \
    p0b = MFMA(S##7, bf[0][7], p0b,0,0,0); \
    p1b = MFMA(S##7, bf[1][7], p1b,0,0,0); \
    int mb_ = wave*192 + (mtv)*16 + quad*4; \
    _Pragma("unroll") \
    for (int r_ = 0; r_ < 4; r_++) { \
        int m_ = mb_ + r_; \
        int base_ = (m_ & 255)*YSTR + (m_ >> 8)*32 + l16; \
        Yt[base_]      = f2bf(p0a[r_] + p0b[r_]); \
        Yt[base_ + 16] = f2bf(p1a[r_] + p1b[r_]); \
    } }

    PLD(wA, 0); PLD(wB, 1); PLD(wC, 2);
    #pragma unroll 1
    for (int mt = 0; mt < 9; mt += 3) {
        PMFW(wA, mt);     PLD(wA, mt + 3);
        PMFW(wB, mt + 1); PLD(wB, mt + 4);
        PMFW(wC, mt + 2); PLD(wC, mt + 5);
    }
    PMFW(wA, 9); PMFW(wB, 10); PMFW(wC, 11);
#undef PLD
#undef PMFW
    __syncthreads();

    // ---- phase 2: Z[c][w] = sum_{k,v} Yt[c][k*32+v] * Al[k][v][w] ----
    f32x4 z[4][2];
    #pragma unroll
    for (int mt = 0; mt < 4; mt++) { z[mt][0] = (f32x4){}; z[mt][1] = (f32x4){}; }
    #pragma unroll
    for (int mt = 0; mt < 4; mt++)
        #pragma unroll
        for (int s = 0; s < 3; s++) {
            bf16x8 a = *(const bf16x8*)(Yt + (wave*64 + mt*16 + l16)*YSTR + s*32 + quad*8);
            z[mt][0] = MFMA(a, al[0][s], z[mt][0], 0,0,0);
            z[mt][1] = MFMA(a, al[1][s], z[mt][1], 0,0,0);
        }

    // ---- bias fold + LN1 + ReLU -> Ut2next ----
    float s_ = 0.f, q_ = 0.f;
    #pragma unroll
    for (int mt = 0; mt < 4; mt++)
        #pragma unroll
        for (int nt = 0; nt < 2; nt++)
            #pragma unroll
            for (int r = 0; r < 4; r++) {
                int c = wave*64 + mt*16 + quad*4 + r;
                int w = nt*16 + l16;
                float zb = z[mt][nt][r] + bgAl[c*32 + w];
                z[mt][nt][r] = zb;
                if (w < VV) { s_ += zb; q_ += zb*zb; }
            }
    blk_reduce2(s_, q_, red);
    float m = s_ * (1.f/6400.f);
    float var = q_ * (1.f/6400.f) - m*m;
    float rs = rsqrtf(var + 1e-5f);
    #pragma unroll
    for (int mt = 0; mt < 4; mt++)
        #pragma unroll
        for (int nt = 0; nt < 2; nt++) {
            int w = nt*16 + l16;
            if (w < VV) {
                int c0 = wave*64 + mt*16 + quad*4;
                ushort4 pk;
                float u0 = fmaxf((z[mt][nt][0]-m)*rs*lnw[(c0+0)*VV+w] + lnb[(c0+0)*VV+w], 0.f);
                float u1 = fmaxf((z[mt][nt][1]-m)*rs*lnw[(c0+1)*VV+w] + lnb[(c0+1)*VV+w], 0.f);
                float u2 = fmaxf((z[mt][nt][2]-m)*rs*lnw[(c0+2)*VV+w] + lnb[(c0+2)*VV+w], 0.f);
                float u3 = fmaxf((z[mt][nt][3]-m)*rs*lnw[(c0+3)*VV+w] + lnb[(c0+3)*VV+w], 0.f);
                pk.x = f2bf(u0); pk.y = f2bf(u1); pk.z = f2bf(u2); pk.w = f2bf(u3);
                *(ushort4*)(Ut2next + (size_t)((t+8)*32 + w)*CC + c0) = pk;
            }
        }
    #pragma unroll
    for (int r = VV; r < 32; r++)
        Ut2next[(size_t)((t+8)*32 + r)*CC + tid] = 0;
}

// ---------------- final: tcn(u_8) + LN2 + residual + ReLU + pool + classifier ----------------

__global__ __launch_bounds__(256, 1) void k_fin(
    const us16* __restrict__ Wt2, const us16* __restrict__ Ut2prev,
    const us16* __restrict__ HresidTb,
    const float* __restrict__ btv,
    const float* __restrict__ lnw, const float* __restrict__ lnb,
    const float* __restrict__ Wout, const float* __restrict__ bout,
    float* __restrict__ out) {
    const int t = blockIdx.x, tid = threadIdx.x;
    const int wave = tid >> 6, lane = tid & 63, quad = lane >> 4, l16 = lane & 15;
    __shared__ float red[8];
    __shared__ float so[CC*33];

    f32x4 acc[4][2];
    #pragma unroll
    for (int mt = 0; mt < 4; mt++) { acc[mt][0] = (f32x4){}; acc[mt][1] = (f32x4){}; }
    const us16* wp0 = Wt2 + (size_t)(wave*64 + l16)*KDIM2 + quad*8;
    bf16x8 tXa0,tXa1,tXa2,tXa3,tXb0,tXb1;
    bf16x8 tYa0,tYa1,tYa2,tYa3,tYb0,tYb1;
    bf16x8 tZa0,tZa1,tZa2,tZa3,tZb0,tZb1;
    TLD(tX, 0); TLD(tY, 1); TLD(tZ, 2);
    #pragma unroll 1
    for (int it = 3; it < 72; it += 3) {
        TMF(tX); TLD(tX, it);
        TMF(tY); TLD(tY, it + 1);
        TMF(tZ); TLD(tZ, it + 2);
    }
    TMF(tX); TMF(tY); TMF(tZ);

    float s_ = 0.f, q_ = 0.f;
    #pragma unroll
    for (int mt = 0; mt < 4; mt++)
        #pragma unroll
        for (int nt = 0; nt < 2; nt++)
            #pragma unroll
            for (int r = 0; r < 4; r++) {
                int c = wave*64 + mt*16 + quad*4 + r;
                int v = nt*16 + l16;
                float val = acc[mt][nt][r] + btv[c];
                acc[mt][nt][r] = val;
                if (v < VV) { s_ += val; q_ += val*val; }
            }
    blk_reduce2(s_, q_, red);
    float m = s_ * (1.f/6400.f);
    float var = q_ * (1.f/6400.f) - m*m;
    float rs = rsqrtf(var + 1e-5f);
    #pragma unroll
    for (int mt = 0; mt < 4; mt++)
        #pragma unroll
        for (int nt = 0; nt < 2; nt++) {
            int v = nt*16 + l16;
            if (v < VV) {
                int c0 = wave*64 + mt*16 + quad*4;
                #pragma unroll
                for (int r = 0; r < 4; r++) {
                    int c = c0 + r;
                    float res = (t >= 4) ? bf2f(HresidTb[(size_t)((t-4)*32 + v)*CC + c]) : 0.f;
                    so[c*33 + v] = fmaxf((acc[mt][nt][r]-m)*rs*lnw[c*VV+v] + lnb[c*VV+v] + res, 0.f);
                }
            }
        }
    __syncthreads();
    int c = tid;
    float pl = 0.f;
    #pragma unroll
    for (int v = 0; v < VV; v++) pl += so[c*33 + v];
    so[c*33 + 32] = pl * (1.f/VV);
    __syncthreads();
    if (tid < NCC) {
        float a = bout[tid];
        for (int cc = 0; cc < CC; cc++) a = fmaf(Wout[tid*CC+cc], so[cc*33 + 32], a);
        out[t*NCC + tid] = a;
    }
}

// ---------------- launch ----------------

extern "C" void kernel_launch(void* const* d_in, const int* in_sizes, int n_in,
                              void* d_out, int out_size, void* d_ws, size_t ws_size,
                              hipStream_t stream) {
    const float* x    = (const float*)d_in[0];
    const float* A    = (const float*)d_in[1];
    const float* lniw = (const float*)d_in[2];
    const float* lnib = (const float*)d_in[3];
    const float* Win  = (const float*)d_in[4];
    const float* bin  = (const float*)d_in[5];
    const float* Wg   = (const float*)d_in[6];
    const float* bg   = (const float*)d_in[7];
    const float* ln1w = (const float*)d_in[8];
    const float* ln1b = (const float*)d_in[9];
    const float* Wt   = (const float*)d_in[10];
    const float* bt   = (const float*)d_in[11];
    const float* ln2w = (const float*)d_in[12];
    const float* ln2b = (const float*)d_in[13];
    const float* imp  = (const float*)d_in[14];
    const float* Wout = (const float*)d_in[15];
    const float* bout = (const float*)d_in[16];
    float* out = (float*)d_out;

    float* ws = (float*)d_ws;
    size_t off = 0;
    auto alloc = [&](size_t n) { float* p = ws + off; off += (n + 255) & ~(size_t)255; return p; };
    float* bgAl = alloc((size_t)LL*CC*32);
    us16* HTb0 = (us16*)alloc((size_t)TT*32*CC/2);
    us16* HTb1 = (us16*)alloc((size_t)TT*32*CC/2);
    us16* Wgb  = (us16*)alloc((size_t)LL*KK*CC*CC/2);
    us16* Wt2b = (us16*)alloc((size_t)LL*CC*KDIM2/2);
    us16* UtA  = (us16*)alloc((size_t)UR*CC/2);
    us16* UtB  = (us16*)alloc((size_t)UR*CC/2);
    us16* AlTb = (us16*)alloc((size_t)LL*KK*32*32/2);
    (void)ws_size; (void)in_sizes; (void)n_in; (void)out_size;

    k_prep<<<(PTOT + 255)/256, 256, 0, stream>>>(Wg, Wt, A, imp, bg,
                                                 Wgb, Wt2b, AlTb, bgAl);

    us16* hPrev = HTb0; us16* hNext = HTb1;
    us16* uCur = UtA;  us16* uNxt = UtB;
    for (int l = 0; l < LL; l++) {
        if (l == 0) {
            k_layer<1><<<TT + 8, 256, 0, stream>>>(
                x, lniw, lnib, Win, bin,
                Wt2b, uCur, bt, ln2w, ln2b, hPrev,    // tcn args unused in FIRST
                Wgb, AlTb, bgAl, ln1w, ln1b,
                hPrev /* writes h^0 */, uCur /* writes u_0 */);
        } else {
            k_layer<0><<<TT + 8, 256, 0, stream>>>(
                x, lniw, lnib, Win, bin,
                Wt2b + (size_t)(l-1)*CC*KDIM2, uCur,
                bt + (size_t)(l-1)*CC,
                ln2w + (size_t)(l-1)*CC*VV, ln2b + (size_t)(l-1)*CC*VV,
                hPrev /* residual */,
                Wgb + (size_t)l*KK*CC*CC,
                AlTb + (size_t)l*KK*32*32, bgAl + (size_t)l*CC*32,
                ln1w + (size_t)l*CC*VV, ln1b + (size_t)l*CC*VV,
                hNext /* writes h^{l-1}->next resid */, uNxt /* writes u_l */);
            us16* tmp = hPrev; hPrev = hNext; hNext = tmp;
            us16* ut = uCur; uCur = uNxt; uNxt = ut;
        }
    }
    k_fin<<<TT, 256, 0, stream>>>(
        Wt2b + (size_t)(LL-1)*CC*KDIM2, uCur, hPrev,
        bt + (size_t)(LL-1)*CC, ln2w + (size_t)(LL-1)*CC*VV, ln2b + (size_t)(LL-1)*CC*VV,
        Wout, bout, out);
}